// Round 1
// baseline (324.428 us; speedup 1.0000x reference)
//
#include <hip/hip_runtime.h>

// LightshiftaddLayer — R6: gemm_bt restructured to the proven 2-phase
// double-buffered template:
//   - ONE barrier per K-step (LDS double-buffer) instead of two
//   - B tile staged via global_load_lds width=16 (no VGPR round trip);
//     linear LDS dest + pre-swizzled global source (m173/m201 pattern)
//   - T2 XOR swizzle byte^=((row&7)<<4) on both LDS tiles: the stride-40
//     pad was still 8-way conflicted (8.4M conflict cycles/dispatch)
//   - BK 32->64: 8 steps instead of 16, 32 MFMA per phase of latency cover
//   - loads for step s+1 issued BEFORE compute of step s (T14 issue-early)
// lconv: CHT 32->16 (grid 512->1024 blocks, 2->4 blocks/CU).
constexpr int T_DIM = 4096;
constexpr int B_DIM = 16;
constexpr int C_DIM = 512;
constexpr int K_CONV = 7;
constexpr int M_DIM = T_DIM * B_DIM;   // 65536 GEMM rows
constexpr int BC = B_DIM * C_DIM;      // 8192

typedef __attribute__((ext_vector_type(8))) short bf16x8;
typedef __attribute__((ext_vector_type(4))) float f32x4;
typedef __attribute__((ext_vector_type(8))) float f32x8;
typedef __attribute__((ext_vector_type(4))) unsigned int u32x4;
typedef __attribute__((ext_vector_type(2))) unsigned int u32x2;

__device__ __forceinline__ unsigned short f2bf(float f) {
  unsigned u = __float_as_uint(f);
  u += 0x7fffu + ((u >> 16) & 1u);   // RNE
  return (unsigned short)(u >> 16);
}
__device__ __forceinline__ unsigned pack2(float a, float b) {
  return (unsigned)f2bf(a) | (((unsigned)f2bf(b)) << 16);
}

// ---------------------------------------------------------------- quantize W -> bf16
__global__ __launch_bounds__(256) void quantize_w(
    const float* __restrict__ W, unsigned short* __restrict__ Wq) {
  int i = blockIdx.x * 256 + threadIdx.x;
  float w = W[i];
  float a = fabsf(w) + 1e-12f;
  float q = exp2f(rintf(log2f(a)));       // rintf = RNE, matches jnp.round
  q = (w > 0.f) ? q : ((w < 0.f) ? -q : 0.f);
  Wq[i] = f2bf(q);                        // powers of two: exact in bf16
}

// ---------------------------------------------------------------- GEMM (B^T)
// Y[m,n] = sum_k X[m,k]*Bt[n,k] + bias[n]; X fp32 cast in-flight, Bt bf16.
constexpr int BK = 64;
constexpr int NSTEP = C_DIM / BK;   // 8 K-steps

__global__ __launch_bounds__(256, 2) void gemm_bt(
    const float* __restrict__ X, const short* __restrict__ Bt,
    const float* __restrict__ bias, unsigned short* __restrict__ Y) {
  constexpr int K = C_DIM, N = C_DIM;
  // 128 rows x 64 k, bf16, 128 B/row, XOR-swizzled chunks. 16 KB per tile,
  // double-buffered A and B = 64 KB total -> 2 blocks/CU.
  __shared__ __align__(16) short As[2][128 * BK];
  __shared__ __align__(16) short Bs[2][128 * BK];

  // XCD swizzle: ids 8 apart share an X m-tile and land on one XCD.
  const int id   = blockIdx.x;            // 0..2047
  const int xcd  = id & 7;
  const int slot = id >> 3;               // 0..255
  const int nb   = slot & 3;
  const int mb   = xcd * 64 + (slot >> 2);
  const int m0 = mb * 128;
  const int n0 = nb * 128;

  const int t    = threadIdx.x;
  const int lane = t & 63;
  const int wid  = t >> 6;               // 4 waves: 2x2 of 64x64

  // ---- A staging (reg round trip for fp32->bf16):
  // instr j (0..7): fully-coalesced f32x4 at row j*16+(t>>4), float col (t&15)*4
  const int arow = t >> 4;               // 0..15 (+ j*16)
  const int acol = (t & 15) * 4;         // 0..60
  const float* pA = X + (long)(m0 + arow) * K + acol;
  // ds_write byte-offset within row: swizzled 16B chunk + 8B half
  const int awoff = ((((acol >> 3) ^ (arow & 7)) << 4) | ((acol & 4) << 1));

  // ---- B staging via global_load_lds: LDS dest is linear (wave base +
  // lane*16); the SOURCE address carries the inverse swizzle so that a
  // swizzled ds_read returns the right data. Physical byte p covers
  // row = p>>7, phys chunk = (p>>4)&7, logical chunk = phys ^ (row&7).
  const int brow = (wid << 5) + (lane >> 3);                  // + i*8
  const int bcol = ((lane & 7) ^ ((lane >> 3) & 7)) * 8;      // logical chunk*8
  const short* pB = Bt + (long)(n0 + brow) * K + bcol;

  // ---- fragment geometry (A frag: A[m=lane&15][k=(lane>>4)*8+j])
  const int fr = lane & 15;
  const int fq = lane >> 4;
  const int wm = (wid >> 1) * 64;
  const int wn = (wid & 1) * 64;
  const int sw0 = ((fq ^ (fr & 7)) << 4);          // kk=0 chunk swizzle
  const int sw1 = (((4 + fq) ^ (fr & 7)) << 4);    // kk=1 chunk swizzle

  f32x4 ax[8];
  f32x4 acc[4][4] = {};

  auto loadA = [&](int k0) {
#pragma unroll
    for (int j = 0; j < 8; ++j)
      ax[j] = *(const f32x4*)(pA + (long)j * 16 * K + k0);
  };
  auto stageB = [&](int bsel, int k0) {
#pragma unroll
    for (int i = 0; i < 4; ++i)
      __builtin_amdgcn_global_load_lds(
          (const __attribute__((address_space(1))) void*)(pB + (long)i * 8 * K + k0),
          (__attribute__((address_space(3))) void*)&Bs[bsel][wid * 2048 + i * 512],
          16, 0, 0);
  };
  auto writeA = [&](int bsel) {
    char* base = (char*)&As[bsel][0];
#pragma unroll
    for (int j = 0; j < 8; ++j) {
      u32x2 p;
      p[0] = pack2(ax[j][0], ax[j][1]);
      p[1] = pack2(ax[j][2], ax[j][3]);
      *(u32x2*)(base + (j * 16 + arow) * 128 + awoff) = p;
    }
  };
  auto compute = [&](int bsel) {
    const char* ab = (const char*)&As[bsel][0];
    const char* bb = (const char*)&Bs[bsel][0];
#pragma unroll
    for (int kk = 0; kk < 2; ++kk) {
      const int sw = kk ? sw1 : sw0;
      bf16x8 af[4], bfr[4];
#pragma unroll
      for (int i = 0; i < 4; ++i)
        af[i] = *(const bf16x8*)(ab + (wm + i * 16 + fr) * 128 + sw);
#pragma unroll
      for (int j = 0; j < 4; ++j)
        bfr[j] = *(const bf16x8*)(bb + (wn + j * 16 + fr) * 128 + sw);
#pragma unroll
      for (int i = 0; i < 4; ++i)
#pragma unroll
        for (int j = 0; j < 4; ++j)
          acc[i][j] = __builtin_amdgcn_mfma_f32_16x16x32_bf16(af[i], bfr[j], acc[i][j], 0, 0, 0);
    }
  };

  // prologue: stage tile 0
  loadA(0);
  stageB(0, 0);
  writeA(0);                 // compiler inserts vmcnt wait for ax only
  __syncthreads();           // drains B gloads too

  // main loop: ONE barrier per step; loads for s+1 in flight across compute(s)
#pragma unroll
  for (int s = 0; s < NSTEP; ++s) {
    const int buf = s & 1;
    if (s + 1 < NSTEP) {
      loadA((s + 1) * BK);           // issue early — hides under compute
      stageB(buf ^ 1, (s + 1) * BK);
    }
    compute(buf);
    if (s + 1 < NSTEP) {
      writeA(buf ^ 1);               // other buffer: no barrier needed before
      __syncthreads();               // publishes As/Bs[buf^1], retires reads of [buf]
    }
  }

  // epilogue: C/D layout col=lane&15, row=(lane>>4)*4+reg
#pragma unroll
  for (int j = 0; j < 4; ++j) {
    const int gn = n0 + wn + j * 16 + fr;
    const float bv = bias[gn];
#pragma unroll
    for (int i = 0; i < 4; ++i) {
#pragma unroll
      for (int r = 0; r < 4; ++r) {
        const int gm = m0 + wm + i * 16 + fq * 4 + r;
        Y[(long)gm * N + gn] = f2bf(acc[i][j][r] + bv);
      }
    }
  }
}

// ---------------------------------------------------------------- depthwise conv
// out[t,b,c] = sum_k y[t+k-3,b,c] * softmax(weight[h])[k], h = c>>6.
constexpr int CHT = 16;   // t's per thread (32->16: 1024 blocks, 4/CU)

__device__ __forceinline__ u32x4 loadY(const unsigned short* Y, int t, long off) {
  if ((unsigned)t < (unsigned)T_DIM)
    return *(const u32x4*)(Y + (long)t * BC + off);
  u32x4 z = {0u, 0u, 0u, 0u};
  return z;
}

__device__ __forceinline__ f32x8 unpack8(u32x4 u) {
  f32x8 r;
#pragma unroll
  for (int i = 0; i < 4; ++i) {
    unsigned w = u[i];
    r[2 * i]     = __uint_as_float(w << 16);
    r[2 * i + 1] = __uint_as_float(w & 0xffff0000u);
  }
  return r;
}

__global__ __launch_bounds__(256) void lconv(
    const unsigned short* __restrict__ Y, const float* __restrict__ W,
    float* __restrict__ O) {
  const int tid  = blockIdx.x * 256 + threadIdx.x;
  const int cvec = tid & 63;               // 8-channel vector index
  const int b    = (tid >> 6) & 15;
  const int tc   = tid >> 10;              // t chunk
  const int t0   = tc * CHT;
  const long off = (long)b * C_DIM + cvec * 8;
  const int h    = cvec >> 3;              // head = c/64

  // softmax over the head's 7 taps (fp32, matches ref)
  float wf[K_CONV];
  float mx = -1e30f;
#pragma unroll
  for (int k = 0; k < K_CONV; ++k) { wf[k] = W[h * K_CONV + k]; mx = fmaxf(mx, wf[k]); }
  float s = 0.f;
#pragma unroll
  for (int k = 0; k < K_CONV; ++k) { wf[k] = __expf(wf[k] - mx); s += wf[k]; }
  const float inv = 1.f / s;
#pragma unroll
  for (int k = 0; k < K_CONV; ++k) wf[k] *= inv;

  f32x8 win[K_CONV];
#pragma unroll
  for (int i = 0; i < 6; ++i) win[i] = unpack8(loadY(Y, t0 - 3 + i, off));

#pragma unroll
  for (int j = 0; j < CHT; ++j) {
    win[6] = unpack8(loadY(Y, t0 + 3 + j, off));
    f32x8 acc = win[0] * wf[0];
#pragma unroll
    for (int k = 1; k < K_CONV; ++k) acc += win[k] * wf[k];
    float* op = O + (long)(t0 + j) * BC + off;
    *(f32x4*)op       = f32x4{acc[0], acc[1], acc[2], acc[3]};
    *(f32x4*)(op + 4) = f32x4{acc[4], acc[5], acc[6], acc[7]};
#pragma unroll
    for (int k = 0; k < 6; ++k) win[k] = win[k + 1];
  }
}

// ---------------------------------------------------------------- launch
extern "C" void kernel_launch(void* const* d_in, const int* in_sizes, int n_in,
                              void* d_out, int out_size, void* d_ws, size_t ws_size,
                              hipStream_t stream) {
  const float* x       = (const float*)d_in[0];  // (T,B,C) fp32
  const float* shift_W = (const float*)d_in[1];  // (C,C) fp32
  const float* shift_b = (const float*)d_in[2];  // (C) fp32
  const float* weight  = (const float*)d_in[3];  // (8,7) fp32
  float* out = (float*)d_out;

  unsigned short* Wq = (unsigned short*)d_ws;        // 512 KB bf16 Wq
  unsigned short* Y  = Wq + C_DIM * C_DIM;           // 67 MB bf16 y

  quantize_w<<<(C_DIM * C_DIM) / 256, 256, 0, stream>>>(shift_W, Wq);
  gemm_bt<<<(M_DIM / 128) * (C_DIM / 128), 256, 0, stream>>>(
      x, (const short*)Wq, shift_b, Y);
  lconv<<<(M_DIM / CHT) * (C_DIM / 8) / 256, 256, 0, stream>>>(Y, weight, out);
}

// Round 2
// 296.577 us; speedup vs baseline: 1.0939x; 1.0939x over previous
//
#include <hip/hip_runtime.h>

// LightshiftaddLayer — R7:
//  lconv: REWRITTEN. One output t per thread (no window shift-register):
//    7 independent 16B loads, ~55 VGPR -> 16 waves/CU (was ~2 blocks/CU with
//    56-VGPR f32x8 window). Y re-read 7x is L2/L3-served: XCD swizzle gives
//    each XCD a contiguous 512-t slice per b. Softmax once per block via LDS.
//  gemm_bt: keep single-barrier dbuf + T2 swizzle + gload_lds(B), but BK
//    64->32 -> 32 KB LDS -> 4 blocks/CU (R6 dropped occupancy to 2 blocks;
//    TLP, not intra-block depth, hides the barrier drain at K=512).
//    64B-row swizzle: chunk ^= (row>>1)&3 -> 2 lanes/bank-group (free, m136).
constexpr int T_DIM = 4096;
constexpr int B_DIM = 16;
constexpr int C_DIM = 512;
constexpr int K_CONV = 7;
constexpr int M_DIM = T_DIM * B_DIM;   // 65536 GEMM rows
constexpr int BC = B_DIM * C_DIM;      // 8192

typedef __attribute__((ext_vector_type(8))) short bf16x8;
typedef __attribute__((ext_vector_type(4))) float f32x4;
typedef __attribute__((ext_vector_type(8))) float f32x8;
typedef __attribute__((ext_vector_type(4))) unsigned int u32x4;

__device__ __forceinline__ unsigned short f2bf(float f) {
  unsigned u = __float_as_uint(f);
  u += 0x7fffu + ((u >> 16) & 1u);   // RNE
  return (unsigned short)(u >> 16);
}
__device__ __forceinline__ unsigned pack2(float a, float b) {
  return (unsigned)f2bf(a) | (((unsigned)f2bf(b)) << 16);
}

// ---------------------------------------------------------------- quantize W -> bf16
__global__ __launch_bounds__(256) void quantize_w(
    const float* __restrict__ W, unsigned short* __restrict__ Wq) {
  int i = blockIdx.x * 256 + threadIdx.x;
  float w = W[i];
  float a = fabsf(w) + 1e-12f;
  float q = exp2f(rintf(log2f(a)));       // rintf = RNE, matches jnp.round
  q = (w > 0.f) ? q : ((w < 0.f) ? -q : 0.f);
  Wq[i] = f2bf(q);                        // powers of two: exact in bf16
}

// ---------------------------------------------------------------- GEMM (B^T)
// Y[m,n] = sum_k X[m,k]*Bt[n,k] + bias[n]; X fp32 cast in-flight, Bt bf16.
constexpr int BK = 32;
constexpr int NSTEP = C_DIM / BK;   // 16 K-steps

__global__ __launch_bounds__(256, 4) void gemm_bt(
    const float* __restrict__ X, const short* __restrict__ Bt,
    const float* __restrict__ bias, unsigned short* __restrict__ Y) {
  constexpr int K = C_DIM, N = C_DIM;
  // 128 rows x 32 k bf16 = 64 B/row, 8 KB/tile; dbuf A+B = 32 KB -> 4 blk/CU.
  __shared__ __align__(16) short As[2][128 * BK];
  __shared__ __align__(16) short Bs[2][128 * BK];

  // XCD swizzle: the 4 n-blocks sharing an X m-tile run consecutively on one XCD.
  const int id   = blockIdx.x;            // 0..2047
  const int xcd  = id & 7;
  const int slot = id >> 3;               // 0..255
  const int nb   = slot & 3;
  const int mb   = xcd * 64 + (slot >> 2);
  const int m0 = mb * 128;
  const int n0 = nb * 128;

  const int t    = threadIdx.x;
  const int lane = t & 63;
  const int wid  = t >> 6;               // 4 waves: 2x2 of 64x64

  // ---- A staging (reg round trip for fp32->bf16):
  // thread t: rows (t>>2) and 64+(t>>2), float col (t&3)*8 (8 floats/row).
  const int ar = t >> 2;                 // 0..63
  const int ac = (t & 3) * 8;
  const float* pA = X + (long)(m0 + ar) * K + ac;
  // swizzled 16B-chunk within 64B row: chunk ^= (row>>1)&3 (same for row+64)
  const int awoff = (((t & 3) ^ ((ar >> 1) & 3)) << 4);

  // ---- B staging via global_load_lds: linear LDS dest (wave base + lane*16),
  // source pre-swizzled. phys: row = i*64 + (t>>2), chunk = t&3; logical
  // chunk = (t&3) ^ ((row>>1)&3) = (t&3) ^ ((t>>3)&3).
  const int bc = ((t & 3) ^ ((t >> 3) & 3)) * 8;   // shorts
  const short* pB = Bt + (long)(n0 + (t >> 2)) * K + bc;

  // ---- fragment geometry (A frag: A[m=lane&15][k=(lane>>4)*8+j])
  const int fr = lane & 15;
  const int fq = lane >> 4;
  const int wm = (wid >> 1) * 64;
  const int wn = (wid & 1) * 64;
  // frag row = wm|wn + i*16 + fr  ->  (row>>1)&3 = (fr>>1)&3 (wave-constant)
  const int sw = ((fq ^ ((fr >> 1) & 3)) << 4);

  f32x4 ax[4];
  f32x4 acc[4][4] = {};

  auto loadA = [&](int k0) {
    ax[0] = *(const f32x4*)(pA + k0);
    ax[1] = *(const f32x4*)(pA + k0 + 4);
    ax[2] = *(const f32x4*)(pA + (long)64 * K + k0);
    ax[3] = *(const f32x4*)(pA + (long)64 * K + k0 + 4);
  };
  auto stageB = [&](int bsel, int k0) {
#pragma unroll
    for (int i = 0; i < 2; ++i)
      __builtin_amdgcn_global_load_lds(
          (const __attribute__((address_space(1))) void*)(pB + (long)i * 64 * K + k0),
          (__attribute__((address_space(3))) void*)&Bs[bsel][i * 2048 + wid * 512],
          16, 0, 0);
  };
  auto writeA = [&](int bsel) {
    char* base = (char*)&As[bsel][0];
    u32x4 p0, p1;
    p0[0] = pack2(ax[0][0], ax[0][1]);
    p0[1] = pack2(ax[0][2], ax[0][3]);
    p0[2] = pack2(ax[1][0], ax[1][1]);
    p0[3] = pack2(ax[1][2], ax[1][3]);
    p1[0] = pack2(ax[2][0], ax[2][1]);
    p1[1] = pack2(ax[2][2], ax[2][3]);
    p1[2] = pack2(ax[3][0], ax[3][1]);
    p1[3] = pack2(ax[3][2], ax[3][3]);
    *(u32x4*)(base + ar * 64 + awoff)        = p0;
    *(u32x4*)(base + (64 + ar) * 64 + awoff) = p1;
  };
  auto compute = [&](int bsel) {
    const char* ab = (const char*)&As[bsel][0];
    const char* bb = (const char*)&Bs[bsel][0];
    bf16x8 af[4], bfr[4];
#pragma unroll
    for (int i = 0; i < 4; ++i)
      af[i] = *(const bf16x8*)(ab + (wm + i * 16 + fr) * 64 + sw);
#pragma unroll
    for (int j = 0; j < 4; ++j)
      bfr[j] = *(const bf16x8*)(bb + (wn + j * 16 + fr) * 64 + sw);
#pragma unroll
    for (int i = 0; i < 4; ++i)
#pragma unroll
      for (int j = 0; j < 4; ++j)
        acc[i][j] = __builtin_amdgcn_mfma_f32_16x16x32_bf16(af[i], bfr[j], acc[i][j], 0, 0, 0);
  };

  // prologue: stage tile 0
  loadA(0);
  stageB(0, 0);
  writeA(0);
  __syncthreads();

  // main loop: ONE barrier per step; s+1 loads in flight across compute(s)
#pragma unroll
  for (int s = 0; s < NSTEP; ++s) {
    const int buf = s & 1;
    if (s + 1 < NSTEP) {
      loadA((s + 1) * BK);
      stageB(buf ^ 1, (s + 1) * BK);
    }
    compute(buf);
    if (s + 1 < NSTEP) {
      writeA(buf ^ 1);
      __syncthreads();
    }
  }

  // epilogue: C/D layout col=lane&15, row=(lane>>4)*4+reg
#pragma unroll
  for (int j = 0; j < 4; ++j) {
    const int gn = n0 + wn + j * 16 + fr;
    const float bv = bias[gn];
#pragma unroll
    for (int i = 0; i < 4; ++i) {
#pragma unroll
      for (int r = 0; r < 4; ++r) {
        const int gm = m0 + wm + i * 16 + fq * 4 + r;
        Y[(long)gm * N + gn] = f2bf(acc[i][j][r] + bv);
      }
    }
  }
}

// ---------------------------------------------------------------- depthwise conv
// out[t,b,c] = sum_k y[t+k-3,b,c] * softmax(weight[h])[k], h = c>>6.
// One t per thread: 7 independent 16B loads, no window state, ~55 VGPR.
__device__ __forceinline__ u32x4 loadY(const unsigned short* Y, int t, long off) {
  if ((unsigned)t < (unsigned)T_DIM)
    return *(const u32x4*)(Y + (long)t * BC + off);
  u32x4 z = {0u, 0u, 0u, 0u};
  return z;
}

__device__ __forceinline__ f32x8 unpack8(u32x4 u) {
  f32x8 r;
#pragma unroll
  for (int i = 0; i < 4; ++i) {
    unsigned w = u[i];
    r[2 * i]     = __uint_as_float(w << 16);
    r[2 * i + 1] = __uint_as_float(w & 0xffff0000u);
  }
  return r;
}

__global__ __launch_bounds__(256, 4) void lconv(
    const unsigned short* __restrict__ Y, const float* __restrict__ W,
    float* __restrict__ O) {
  __shared__ float sm_wf[8 * K_CONV];
  // block softmax: 8 threads, one head each
  if (threadIdx.x < 8) {
    const int h = threadIdx.x;
    float v[K_CONV];
    float mx = -1e30f;
#pragma unroll
    for (int k = 0; k < K_CONV; ++k) { v[k] = W[h * K_CONV + k]; mx = fmaxf(mx, v[k]); }
    float s = 0.f;
#pragma unroll
    for (int k = 0; k < K_CONV; ++k) { v[k] = __expf(v[k] - mx); s += v[k]; }
    const float inv = 1.f / s;
#pragma unroll
    for (int k = 0; k < K_CONV; ++k) sm_wf[h * K_CONV + k] = v[k] * inv;
  }

  // XCD swizzle: xcd owns t in [xcd*512, xcd*512+512) for a given b;
  // consecutive slots on an XCD walk t -> 7x Y re-read is L2-resident.
  const int id   = blockIdx.x;            // 0..16383
  const int xcd  = id & 7;
  const int slot = id >> 3;               // 0..2047
  const int b    = slot >> 7;             // 0..15
  const int tl   = slot & 127;            // 0..127
  const int t    = xcd * 512 + tl * 4 + (threadIdx.x >> 6);
  const int cvec = threadIdx.x & 63;
  const long off = (long)b * C_DIM + cvec * 8;
  const int h    = cvec >> 3;

  u32x4 v[K_CONV];
#pragma unroll
  for (int k = 0; k < K_CONV; ++k) v[k] = loadY(Y, t + k - 3, off);

  __syncthreads();
  float wf[K_CONV];
#pragma unroll
  for (int k = 0; k < K_CONV; ++k) wf[k] = sm_wf[h * K_CONV + k];

  f32x8 acc = unpack8(v[0]) * wf[0];
#pragma unroll
  for (int k = 1; k < K_CONV; ++k) acc += unpack8(v[k]) * wf[k];

  float* op = O + (long)t * BC + off;
  *(f32x4*)op       = f32x4{acc[0], acc[1], acc[2], acc[3]};
  *(f32x4*)(op + 4) = f32x4{acc[4], acc[5], acc[6], acc[7]};
}

// ---------------------------------------------------------------- launch
extern "C" void kernel_launch(void* const* d_in, const int* in_sizes, int n_in,
                              void* d_out, int out_size, void* d_ws, size_t ws_size,
                              hipStream_t stream) {
  const float* x       = (const float*)d_in[0];  // (T,B,C) fp32
  const float* shift_W = (const float*)d_in[1];  // (C,C) fp32
  const float* shift_b = (const float*)d_in[2];  // (C) fp32
  const float* weight  = (const float*)d_in[3];  // (8,7) fp32
  float* out = (float*)d_out;

  unsigned short* Wq = (unsigned short*)d_ws;        // 512 KB bf16 Wq
  unsigned short* Y  = Wq + C_DIM * C_DIM;           // 67 MB bf16 y

  quantize_w<<<(C_DIM * C_DIM) / 256, 256, 0, stream>>>(shift_W, Wq);
  gemm_bt<<<(M_DIM / 128) * (C_DIM / 128), 256, 0, stream>>>(
      x, (const short*)Wq, shift_b, Y);
  lconv<<<M_DIM * (C_DIM / 8) / 256, 256, 0, stream>>>(Y, weight, out);
}